// Round 5
// baseline (494.679 us; speedup 1.0000x reference)
//
#include <hip/hip_runtime.h>

#define EPSN 1e-8f

typedef _Float16 half8 __attribute__((ext_vector_type(8)));
typedef __fp16 fp16x2 __attribute__((ext_vector_type(2)));   // cvt_pkrtz result type
typedef float floatx4 __attribute__((ext_vector_type(4)));

// ---------------- K2: per-(b,p,tb,vq) GEMM + exp-sums ----------------
// WG: 256 threads / 4 waves in 2x2, WG tile 128v x 128t, wave tile 64x64
// (acc = 64 VGPRs -> 4 blocks/CU co-resident = 4 independent waves/SIMD,
// the latency-hiding TLP rounds 1-4 lacked). K=512 in 16 chunks of 32,
// single-buffered LDS, no register prefetch (compiler sinks it anyway).
// vis/text row norms accumulate in registers during staging.
#define LDA 40   // padded halfs per row (80 B: 16B-aligned; frag reads 2-way-free)

__global__ __launch_bounds__(256, 4) void k_main(
    const float* __restrict__ vis, const float* __restrict__ text,
    float* __restrict__ g_rowsum, float* __restrict__ g_colsum,
    float* __restrict__ g_dsum)
{
    __shared__ _Float16 Ash[128 * LDA];   // 10 KB
    __shared__ _Float16 Bsh[128 * LDA];   // 10 KB
    __shared__ float tn2[128];
    __shared__ float vinvS[128];
    __shared__ float rowS[128];
    __shared__ float colS[128];

    const int blk  = blockIdx.x;          // (((b*16+p)*4+tb)*4+vq)
    const int vq   = blk & 3;
    const int tb   = (blk >> 2) & 3;
    const int bp   = blk >> 4;            // b*16 + p
    const int p    = bp & 15;
    const int b    = bp >> 4;
    const int tid  = threadIdx.x;
    const int lane = tid & 63;
    const int wave = tid >> 6;
    const int wy   = wave >> 1;           // v-half of WG tile
    const int wx   = wave & 1;            // t-half of WG tile
    const int m15  = lane & 15;
    const int g4   = lane >> 4;

    if (tid < 128) { rowS[tid] = 0.f; colS[tid] = 0.f; }  // ordered by 1st barrier

    floatx4 acc[4][4];
    floatx4 zf = {0.f, 0.f, 0.f, 0.f};
    #pragma unroll
    for (int mb = 0; mb < 4; ++mb)
        #pragma unroll
        for (int nb = 0; nb < 4; ++nb) acc[mb][nb] = zf;

    // staging: 2 threads per row, 16 contiguous floats (64 B) each
    const int srow = tid >> 1;            // 0..127
    const int sko  = (tid & 1) * 16;
    const float* aPtr =
        vis + (size_t)b * 512 * 512 + (size_t)(vq * 128 + srow) * 512 + sko;
    const float* bPtr =
        text + ((size_t)((b * 512 + tb * 128 + srow) * 16 + p)) * 512 + sko;

    float vsq = 0.f, tsq = 0.f;           // row-norm partials (this thread's 16/32 cols)

    for (int kc = 0; kc < 16; ++kc) {
        float4 a0 = *reinterpret_cast<const float4*>(aPtr);
        float4 a1 = *reinterpret_cast<const float4*>(aPtr + 4);
        float4 a2 = *reinterpret_cast<const float4*>(aPtr + 8);
        float4 a3 = *reinterpret_cast<const float4*>(aPtr + 12);
        float4 b0 = *reinterpret_cast<const float4*>(bPtr);
        float4 b1 = *reinterpret_cast<const float4*>(bPtr + 4);
        float4 b2 = *reinterpret_cast<const float4*>(bPtr + 8);
        float4 b3 = *reinterpret_cast<const float4*>(bPtr + 12);
        aPtr += 32; bPtr += 32;

        vsq += a0.x*a0.x + a0.y*a0.y + a0.z*a0.z + a0.w*a0.w
             + a1.x*a1.x + a1.y*a1.y + a1.z*a1.z + a1.w*a1.w
             + a2.x*a2.x + a2.y*a2.y + a2.z*a2.z + a2.w*a2.w
             + a3.x*a3.x + a3.y*a3.y + a3.z*a3.z + a3.w*a3.w;
        {
            union { half8 v; fp16x2 q[4]; } u;
            u.q[0] = __builtin_amdgcn_cvt_pkrtz(a0.x, a0.y);
            u.q[1] = __builtin_amdgcn_cvt_pkrtz(a0.z, a0.w);
            u.q[2] = __builtin_amdgcn_cvt_pkrtz(a1.x, a1.y);
            u.q[3] = __builtin_amdgcn_cvt_pkrtz(a1.z, a1.w);
            *reinterpret_cast<half8*>(&Ash[srow * LDA + sko]) = u.v;
            u.q[0] = __builtin_amdgcn_cvt_pkrtz(a2.x, a2.y);
            u.q[1] = __builtin_amdgcn_cvt_pkrtz(a2.z, a2.w);
            u.q[2] = __builtin_amdgcn_cvt_pkrtz(a3.x, a3.y);
            u.q[3] = __builtin_amdgcn_cvt_pkrtz(a3.z, a3.w);
            *reinterpret_cast<half8*>(&Ash[srow * LDA + sko + 8]) = u.v;
        }
        tsq += b0.x*b0.x + b0.y*b0.y + b0.z*b0.z + b0.w*b0.w
             + b1.x*b1.x + b1.y*b1.y + b1.z*b1.z + b1.w*b1.w
             + b2.x*b2.x + b2.y*b2.y + b2.z*b2.z + b2.w*b2.w
             + b3.x*b3.x + b3.y*b3.y + b3.z*b3.z + b3.w*b3.w;
        {
            union { half8 v; fp16x2 q[4]; } u;
            u.q[0] = __builtin_amdgcn_cvt_pkrtz(b0.x, b0.y);
            u.q[1] = __builtin_amdgcn_cvt_pkrtz(b0.z, b0.w);
            u.q[2] = __builtin_amdgcn_cvt_pkrtz(b1.x, b1.y);
            u.q[3] = __builtin_amdgcn_cvt_pkrtz(b1.z, b1.w);
            *reinterpret_cast<half8*>(&Bsh[srow * LDA + sko]) = u.v;
            u.q[0] = __builtin_amdgcn_cvt_pkrtz(b2.x, b2.y);
            u.q[1] = __builtin_amdgcn_cvt_pkrtz(b2.z, b2.w);
            u.q[2] = __builtin_amdgcn_cvt_pkrtz(b3.x, b3.y);
            u.q[3] = __builtin_amdgcn_cvt_pkrtz(b3.z, b3.w);
            *reinterpret_cast<half8*>(&Bsh[srow * LDA + sko + 8]) = u.v;
        }
        __syncthreads();
        // ---- MFMA: wave (wy,wx) covers rows [wy*64,+64) x cols [wx*64,+64) ----
        half8 af[4];
        #pragma unroll
        for (int mb = 0; mb < 4; ++mb)
            af[mb] = *reinterpret_cast<const half8*>(
                &Ash[(wy * 64 + mb * 16 + m15) * LDA + g4 * 8]);
        #pragma unroll
        for (int nb = 0; nb < 4; ++nb) {
            half8 bf = *reinterpret_cast<const half8*>(
                &Bsh[(wx * 64 + nb * 16 + m15) * LDA + g4 * 8]);
            #pragma unroll
            for (int mb = 0; mb < 4; ++mb)
                acc[mb][nb] = __builtin_amdgcn_mfma_f32_16x16x32_f16(
                    af[mb], bf, acc[mb][nb], 0, 0, 0);
        }
        __syncthreads();
    }

    // row norms: combine the 2 threads of each row
    vsq += __shfl_xor(vsq, 1);
    tsq += __shfl_xor(tsq, 1);
    if ((tid & 1) == 0) {
        vinvS[srow] = 1.0f / fmaxf(sqrtf(vsq), EPSN);
        tn2[srow]   = 1.0f / fmaxf(sqrtf(tsq), EPSN);
    }
    __syncthreads();

    float tinvc[4];
    #pragma unroll
    for (int nb = 0; nb < 4; ++nb) tinvc[nb] = tn2[wx * 64 + nb * 16 + m15];

    float colpart[4];
    #pragma unroll
    for (int nb = 0; nb < 4; ++nb) colpart[nb] = 0.f;
    float dsum = 0.f;

    // epilogue: scale, exp, row/col partial sums
    #pragma unroll
    for (int mb = 0; mb < 4; ++mb) {
        #pragma unroll
        for (int r = 0; r < 4; ++r) {
            int vloc  = wy * 64 + mb * 16 + g4 * 4 + r;      // C/D row mapping
            int vglob = vq * 128 + vloc;
            float vi  = vinvS[vloc];
            float rp  = 0.f;
            #pragma unroll
            for (int nb = 0; nb < 4; ++nb) {
                float sim  = acc[mb][nb][r] * vi * tinvc[nb];
                int tglob  = tb * 128 + wx * 64 + nb * 16 + m15;  // C/D col mapping
                if (vglob == tglob) dsum += sim;
                float e = __expf(sim);
                rp += e;
                colpart[nb] += e;
            }
            rp += __shfl_xor(rp, 1);
            rp += __shfl_xor(rp, 2);
            rp += __shfl_xor(rp, 4);
            rp += __shfl_xor(rp, 8);
            if (m15 == 0) atomicAdd(&rowS[vloc], rp);   // wx=0,1 waves collide
        }
    }
    // col partials: reduce over the 4 row-groups (g4), then LDS-accumulate
    #pragma unroll
    for (int nb = 0; nb < 4; ++nb) {
        float cp = colpart[nb];
        cp += __shfl_xor(cp, 16);
        cp += __shfl_xor(cp, 32);
        if (lane < 16) atomicAdd(&colS[wx * 64 + nb * 16 + lane], cp);
    }
    if (vq == tb) {   // only diagonal WGs carry diag terms
        #pragma unroll
        for (int off = 1; off < 64; off <<= 1) dsum += __shfl_xor(dsum, off);
        if (lane == 0) atomicAdd(&g_dsum[bp], dsum);
    }
    __syncthreads();
    if (tid < 128) {
        atomicAdd(&g_rowsum[(size_t)bp * 512 + vq * 128 + tid], rowS[tid]);
        atomicAdd(&g_colsum[(size_t)bp * 512 + tb * 128 + tid], colS[tid]);
    }
}

// ---------------- K3: per-(b,p) clip loss ----------------
__global__ __launch_bounds__(256) void k_clip(
    const float* __restrict__ g_rowsum, const float* __restrict__ g_colsum,
    const float* __restrict__ g_dsum, float* __restrict__ clip)
{
    __shared__ float red[4];
    int bp = blockIdx.x, tid = threadIdx.x;
    int lane = tid & 63, wave = tid >> 6;
    float s = 0.f;
    #pragma unroll
    for (int c = 0; c < 2; ++c) {
        int i = c * 256 + tid;
        s += 0.5f * (logf(g_rowsum[(size_t)bp * 512 + i]) +
                     logf(g_colsum[(size_t)bp * 512 + i]));
    }
    #pragma unroll
    for (int off = 1; off < 64; off <<= 1) s += __shfl_xor(s, off);
    if (lane == 0) red[wave] = s;
    __syncthreads();
    if (tid == 0)
        clip[bp] = (red[0] + red[1] + red[2] + red[3] - g_dsum[bp]) * (1.0f / 512.0f);
}

// ---------------- K4: loss / acc / preds ----------------
__global__ __launch_bounds__(256) void k_final(
    const float* __restrict__ clip, const float* __restrict__ output,
    float* __restrict__ out)
{
    __shared__ float cl[256], ou[256], red[4];
    __shared__ int preds[16];
    int tid = threadIdx.x, lane = tid & 63, wave = tid >> 6;
    cl[tid] = clip[tid];
    ou[tid] = output[tid];
    __syncthreads();
    float d = ou[tid] - cl[tid];
    float s = d * d;
    #pragma unroll
    for (int off = 1; off < 64; off <<= 1) s += __shfl_xor(s, off);
    if (lane == 0) red[wave] = s;
    if (tid < 16) {   // preds = argmin over output row (first occurrence)
        float m = ou[tid * 16]; int a = 0;
        for (int q = 1; q < 16; ++q)
            if (ou[tid * 16 + q] < m) { m = ou[tid * 16 + q]; a = q; }
        preds[tid] = a;
    }
    __syncthreads();
    if (tid == 0) {
        int cnt = 0;
        for (int bb = 0; bb < 16; ++bb) {
            float m = cl[bb * 16]; int a = 0;
            for (int q = 1; q < 16; ++q)
                if (cl[bb * 16 + q] < m) { m = cl[bb * 16 + q]; a = q; }
            cnt += (preds[bb] == a);
        }
        out[0] = (red[0] + red[1] + red[2] + red[3]) * (1.0f / 256.0f);
        out[1] = (float)cnt * (100.0f / 16.0f);
    }
    __syncthreads();
    for (int j = tid; j < 16 * 512; j += 256)
        out[2 + j] = (float)preds[j >> 9];
}

extern "C" void kernel_launch(void* const* d_in, const int* in_sizes, int n_in,
                              void* d_out, int out_size, void* d_ws, size_t ws_size,
                              hipStream_t stream)
{
    const float* output = (const float*)d_in[0];   // (16,16)
    const float* text   = (const float*)d_in[1];   // (16,512,16,512)
    const float* vis    = (const float*)d_in[2];   // (16,512,512)

    float* g_rowsum = (float*)d_ws;                // 256*512
    float* g_colsum = g_rowsum + 256 * 512;        // 256*512
    float* g_dsum   = g_colsum + 256 * 512;        // 256
    float* clip     = g_dsum + 256;                // 256
    // zero rowsum + colsum + dsum (atomic accumulation targets)
    (void)hipMemsetAsync(d_ws, 0, (size_t)(2 * 256 * 512 + 256) * sizeof(float), stream);

    k_main <<<4096, 256, 0, stream>>>(vis, text, g_rowsum, g_colsum, g_dsum);
    k_clip <<<256, 256, 0, stream>>>(g_rowsum, g_colsum, g_dsum, clip);
    k_final<<<1, 256, 0, stream>>>(clip, output, (float*)d_out);
}

// Round 6
// 475.446 us; speedup vs baseline: 1.0405x; 1.0405x over previous
//
#include <hip/hip_runtime.h>

#define EPSN 1e-8f

typedef _Float16 half8 __attribute__((ext_vector_type(8)));
typedef __fp16 fp16x2 __attribute__((ext_vector_type(2)));   // cvt_pkrtz result type
typedef float floatx4 __attribute__((ext_vector_type(4)));

// ---------------- K1: vis inverse norms (wave per row) ----------------
// vis norms were recomputed 64x redundantly inside k_main; one 16 MB pass
// (~4 us) removes 16 FMAs/thread/chunk from the hot kernel.
__global__ __launch_bounds__(256) void k_vinv(const float* __restrict__ vis,
                                              float* __restrict__ vinv) {
    int row  = blockIdx.x * 4 + (threadIdx.x >> 6);   // 8192 rows total
    int lane = threadIdx.x & 63;
    const float4* src = reinterpret_cast<const float4*>(vis + (size_t)row * 512);
    float4 a = src[lane];
    float4 b = src[lane + 64];
    float s = a.x*a.x + a.y*a.y + a.z*a.z + a.w*a.w
            + b.x*b.x + b.y*b.y + b.z*b.z + b.w*b.w;
    #pragma unroll
    for (int off = 1; off < 64; off <<= 1) s += __shfl_xor(s, off);
    if (lane == 0) vinv[row] = 1.0f / fmaxf(sqrtf(s), EPSN);
}

// ---------------- K2: per-(b,p,tb,vq) GEMM + exp-sums ----------------
// WG: 256 threads / 4 waves in 2x2, WG tile 128v x 128t, wave tile 64x64.
// XCD-aware swizzle: the 4 vq WGs sharing one (b,p,tb) text tile are mapped
// to consecutive logical ids on the SAME XCD (round-robin pid%8 = XCD), so
// the 256 KB text tile is served from that XCD's L2 instead of 4 HBM pulls.
#define LDA 40   // padded halfs per row (80 B: 16B-aligned; frag reads 2-way-free)

__global__ __launch_bounds__(256, 4) void k_main(
    const float* __restrict__ vis, const float* __restrict__ text,
    const float* __restrict__ vinv,
    float* __restrict__ g_rowsum, float* __restrict__ g_colsum,
    float* __restrict__ g_dsum)
{
    __shared__ _Float16 Ash[128 * LDA];   // 10 KB
    __shared__ _Float16 Bsh[128 * LDA];   // 10 KB
    __shared__ float tn2[128];
    __shared__ float vinvS[128];
    __shared__ float rowS[128];
    __shared__ float colS[128];

    // ---- XCD swizzle: twins (same s>>2, same xcd, s&3=0..3) share text tile
    const int pid = blockIdx.x;
    const int xcd = pid & 7;
    const int s_  = pid >> 3;
    const int blk = (s_ & 3) + (xcd << 2) + ((s_ >> 2) << 5);   // bijection on 4096

    const int vq   = blk & 3;
    const int tb   = (blk >> 2) & 3;
    const int bp   = blk >> 4;            // b*16 + p
    const int p    = bp & 15;
    const int b    = bp >> 4;
    const int tid  = threadIdx.x;
    const int lane = tid & 63;
    const int wave = tid >> 6;
    const int wy   = wave >> 1;           // v-half of WG tile
    const int wx   = wave & 1;            // t-half of WG tile
    const int m15  = lane & 15;
    const int g4   = lane >> 4;

    if (tid < 128) {                      // ordered by first in-loop barrier
        rowS[tid] = 0.f; colS[tid] = 0.f;
        vinvS[tid] = vinv[b * 512 + vq * 128 + tid];
    }

    floatx4 acc[4][4];
    floatx4 zf = {0.f, 0.f, 0.f, 0.f};
    #pragma unroll
    for (int mb = 0; mb < 4; ++mb)
        #pragma unroll
        for (int nb = 0; nb < 4; ++nb) acc[mb][nb] = zf;

    // staging: 2 threads per row, 16 contiguous floats (64 B) each
    const int srow = tid >> 1;            // 0..127
    const int sko  = (tid & 1) * 16;
    const float* aPtr =
        vis + (size_t)b * 512 * 512 + (size_t)(vq * 128 + srow) * 512 + sko;
    const float* bPtr =
        text + ((size_t)((b * 512 + tb * 128 + srow) * 16 + p)) * 512 + sko;

    float tsq = 0.f;                      // text row-norm partial (16/32 cols)

    for (int kc = 0; kc < 16; ++kc) {
        float4 a0 = *reinterpret_cast<const float4*>(aPtr);
        float4 a1 = *reinterpret_cast<const float4*>(aPtr + 4);
        float4 a2 = *reinterpret_cast<const float4*>(aPtr + 8);
        float4 a3 = *reinterpret_cast<const float4*>(aPtr + 12);
        float4 b0 = *reinterpret_cast<const float4*>(bPtr);
        float4 b1 = *reinterpret_cast<const float4*>(bPtr + 4);
        float4 b2 = *reinterpret_cast<const float4*>(bPtr + 8);
        float4 b3 = *reinterpret_cast<const float4*>(bPtr + 12);
        aPtr += 32; bPtr += 32;

        {
            union { half8 v; fp16x2 q[4]; } u;
            u.q[0] = __builtin_amdgcn_cvt_pkrtz(a0.x, a0.y);
            u.q[1] = __builtin_amdgcn_cvt_pkrtz(a0.z, a0.w);
            u.q[2] = __builtin_amdgcn_cvt_pkrtz(a1.x, a1.y);
            u.q[3] = __builtin_amdgcn_cvt_pkrtz(a1.z, a1.w);
            *reinterpret_cast<half8*>(&Ash[srow * LDA + sko]) = u.v;
            u.q[0] = __builtin_amdgcn_cvt_pkrtz(a2.x, a2.y);
            u.q[1] = __builtin_amdgcn_cvt_pkrtz(a2.z, a2.w);
            u.q[2] = __builtin_amdgcn_cvt_pkrtz(a3.x, a3.y);
            u.q[3] = __builtin_amdgcn_cvt_pkrtz(a3.z, a3.w);
            *reinterpret_cast<half8*>(&Ash[srow * LDA + sko + 8]) = u.v;
        }
        tsq += b0.x*b0.x + b0.y*b0.y + b0.z*b0.z + b0.w*b0.w
             + b1.x*b1.x + b1.y*b1.y + b1.z*b1.z + b1.w*b1.w
             + b2.x*b2.x + b2.y*b2.y + b2.z*b2.z + b2.w*b2.w
             + b3.x*b3.x + b3.y*b3.y + b3.z*b3.z + b3.w*b3.w;
        {
            union { half8 v; fp16x2 q[4]; } u;
            u.q[0] = __builtin_amdgcn_cvt_pkrtz(b0.x, b0.y);
            u.q[1] = __builtin_amdgcn_cvt_pkrtz(b0.z, b0.w);
            u.q[2] = __builtin_amdgcn_cvt_pkrtz(b1.x, b1.y);
            u.q[3] = __builtin_amdgcn_cvt_pkrtz(b1.z, b1.w);
            *reinterpret_cast<half8*>(&Bsh[srow * LDA + sko]) = u.v;
            u.q[0] = __builtin_amdgcn_cvt_pkrtz(b2.x, b2.y);
            u.q[1] = __builtin_amdgcn_cvt_pkrtz(b2.z, b2.w);
            u.q[2] = __builtin_amdgcn_cvt_pkrtz(b3.x, b3.y);
            u.q[3] = __builtin_amdgcn_cvt_pkrtz(b3.z, b3.w);
            *reinterpret_cast<half8*>(&Bsh[srow * LDA + sko + 8]) = u.v;
        }
        __syncthreads();
        // ---- MFMA: wave (wy,wx) covers rows [wy*64,+64) x cols [wx*64,+64) ----
        half8 af[4];
        #pragma unroll
        for (int mb = 0; mb < 4; ++mb)
            af[mb] = *reinterpret_cast<const half8*>(
                &Ash[(wy * 64 + mb * 16 + m15) * LDA + g4 * 8]);
        #pragma unroll
        for (int nb = 0; nb < 4; ++nb) {
            half8 bf = *reinterpret_cast<const half8*>(
                &Bsh[(wx * 64 + nb * 16 + m15) * LDA + g4 * 8]);
            #pragma unroll
            for (int mb = 0; mb < 4; ++mb)
                acc[mb][nb] = __builtin_amdgcn_mfma_f32_16x16x32_f16(
                    af[mb], bf, acc[mb][nb], 0, 0, 0);
        }
        __syncthreads();
    }

    // text norms: combine the 2 threads of each row
    tsq += __shfl_xor(tsq, 1);
    if ((tid & 1) == 0)
        tn2[srow] = 1.0f / fmaxf(sqrtf(tsq), EPSN);
    __syncthreads();

    float tinvc[4];
    #pragma unroll
    for (int nb = 0; nb < 4; ++nb) tinvc[nb] = tn2[wx * 64 + nb * 16 + m15];

    float colpart[4];
    #pragma unroll
    for (int nb = 0; nb < 4; ++nb) colpart[nb] = 0.f;
    float dsum = 0.f;

    // epilogue: scale, exp, row/col partial sums
    #pragma unroll
    for (int mb = 0; mb < 4; ++mb) {
        #pragma unroll
        for (int r = 0; r < 4; ++r) {
            int vloc  = wy * 64 + mb * 16 + g4 * 4 + r;      // C/D row mapping
            int vglob = vq * 128 + vloc;
            float vi  = vinvS[vloc];
            float rp  = 0.f;
            #pragma unroll
            for (int nb = 0; nb < 4; ++nb) {
                float sim  = acc[mb][nb][r] * vi * tinvc[nb];
                int tglob  = tb * 128 + wx * 64 + nb * 16 + m15;  // C/D col mapping
                if (vglob == tglob) dsum += sim;
                float e = __expf(sim);
                rp += e;
                colpart[nb] += e;
            }
            rp += __shfl_xor(rp, 1);
            rp += __shfl_xor(rp, 2);
            rp += __shfl_xor(rp, 4);
            rp += __shfl_xor(rp, 8);
            if (m15 == 0) atomicAdd(&rowS[vloc], rp);   // wx=0,1 waves collide
        }
    }
    // col partials: reduce over the 4 row-groups (g4), then LDS-accumulate
    #pragma unroll
    for (int nb = 0; nb < 4; ++nb) {
        float cp = colpart[nb];
        cp += __shfl_xor(cp, 16);
        cp += __shfl_xor(cp, 32);
        if (lane < 16) atomicAdd(&colS[wx * 64 + nb * 16 + lane], cp);
    }
    if (vq == tb) {   // only diagonal WGs carry diag terms
        #pragma unroll
        for (int off = 1; off < 64; off <<= 1) dsum += __shfl_xor(dsum, off);
        if (lane == 0) atomicAdd(&g_dsum[bp], dsum);
    }
    __syncthreads();
    if (tid < 128) {
        atomicAdd(&g_rowsum[(size_t)bp * 512 + vq * 128 + tid], rowS[tid]);
        atomicAdd(&g_colsum[(size_t)bp * 512 + tb * 128 + tid], colS[tid]);
    }
}

// ---------------- K3: per-(b,p) clip loss ----------------
__global__ __launch_bounds__(256) void k_clip(
    const float* __restrict__ g_rowsum, const float* __restrict__ g_colsum,
    const float* __restrict__ g_dsum, float* __restrict__ clip)
{
    __shared__ float red[4];
    int bp = blockIdx.x, tid = threadIdx.x;
    int lane = tid & 63, wave = tid >> 6;
    float s = 0.f;
    #pragma unroll
    for (int c = 0; c < 2; ++c) {
        int i = c * 256 + tid;
        s += 0.5f * (logf(g_rowsum[(size_t)bp * 512 + i]) +
                     logf(g_colsum[(size_t)bp * 512 + i]));
    }
    #pragma unroll
    for (int off = 1; off < 64; off <<= 1) s += __shfl_xor(s, off);
    if (lane == 0) red[wave] = s;
    __syncthreads();
    if (tid == 0)
        clip[bp] = (red[0] + red[1] + red[2] + red[3] - g_dsum[bp]) * (1.0f / 512.0f);
}

// ---------------- K4: loss / acc / preds ----------------
__global__ __launch_bounds__(256) void k_final(
    const float* __restrict__ clip, const float* __restrict__ output,
    float* __restrict__ out)
{
    __shared__ float cl[256], ou[256], red[4];
    __shared__ int preds[16];
    int tid = threadIdx.x, lane = tid & 63, wave = tid >> 6;
    cl[tid] = clip[tid];
    ou[tid] = output[tid];
    __syncthreads();
    float d = ou[tid] - cl[tid];
    float s = d * d;
    #pragma unroll
    for (int off = 1; off < 64; off <<= 1) s += __shfl_xor(s, off);
    if (lane == 0) red[wave] = s;
    if (tid < 16) {   // preds = argmin over output row (first occurrence)
        float m = ou[tid * 16]; int a = 0;
        for (int q = 1; q < 16; ++q)
            if (ou[tid * 16 + q] < m) { m = ou[tid * 16 + q]; a = q; }
        preds[tid] = a;
    }
    __syncthreads();
    if (tid == 0) {
        int cnt = 0;
        for (int bb = 0; bb < 16; ++bb) {
            float m = cl[bb * 16]; int a = 0;
            for (int q = 1; q < 16; ++q)
                if (cl[bb * 16 + q] < m) { m = cl[bb * 16 + q]; a = q; }
            cnt += (preds[bb] == a);
        }
        out[0] = (red[0] + red[1] + red[2] + red[3]) * (1.0f / 256.0f);
        out[1] = (float)cnt * (100.0f / 16.0f);
    }
    __syncthreads();
    for (int j = tid; j < 16 * 512; j += 256)
        out[2 + j] = (float)preds[j >> 9];
}

extern "C" void kernel_launch(void* const* d_in, const int* in_sizes, int n_in,
                              void* d_out, int out_size, void* d_ws, size_t ws_size,
                              hipStream_t stream)
{
    const float* output = (const float*)d_in[0];   // (16,16)
    const float* text   = (const float*)d_in[1];   // (16,512,16,512)
    const float* vis    = (const float*)d_in[2];   // (16,512,512)

    float* g_rowsum = (float*)d_ws;                // 256*512
    float* g_colsum = g_rowsum + 256 * 512;        // 256*512
    float* g_dsum   = g_colsum + 256 * 512;        // 256
    float* clip     = g_dsum + 256;                // 256
    float* vinv     = clip + 256;                  // 8192
    // zero rowsum + colsum + dsum (atomic accumulation targets)
    (void)hipMemsetAsync(d_ws, 0, (size_t)(2 * 256 * 512 + 256) * sizeof(float), stream);

    k_vinv <<<2048, 256, 0, stream>>>(vis, vinv);
    k_main <<<4096, 256, 0, stream>>>(vis, text, vinv, g_rowsum, g_colsum, g_dsum);
    k_clip <<<256, 256, 0, stream>>>(g_rowsum, g_colsum, g_dsum, clip);
    k_final<<<1, 256, 0, stream>>>(clip, output, (float*)d_out);
}